// Round 8
// baseline (420.850 us; speedup 1.0000x reference)
//
#include <hip/hip_runtime.h>
#include <hip/hip_bf16.h>

#define NN 50000
#define EE 800000
#define GG 16
#define QD 768
#define NBUCK 196      // ceil(50000/256) dst-buckets of 256 nodes
#define EPB 4000       // edges per block in bin_edges (200 blocks)

#define AGG_GRID 2048            // long-lived blocks: 8/CU
#define AGG_STRIDE (AGG_GRID * 4)

typedef __bf16 bf16x8 __attribute__((ext_vector_type(8)));
typedef float f32x4 __attribute__((ext_vector_type(4)));
typedef int v4i __attribute__((ext_vector_type(4)));

// raw buffer loads (HW bounds check: OOB returns 0 — validated in rounds 6/7).
extern "C" __device__ int __llvm_amdgcn_raw_buffer_load_i32(v4i rsrc, int voffset,
                                                            int soffset, int aux)
    __asm("llvm.amdgcn.raw.buffer.load.i32");

static __device__ __forceinline__ float bflo(unsigned u) {
    union { unsigned v; float f; } c; c.v = u << 16; return c.f;
}
static __device__ __forceinline__ float bfhi(unsigned u) {
    union { unsigned v; float f; } c; c.v = u & 0xffff0000u; return c.f;
}

// ---------- fused prep + bucket_hist, range-dispatched ----------
// WT_k[og][kk], og in [0,5O), kk in [0,128):
//   og < O  -> root[kk][og]
//   else r=(og-O)/O, oo=(og-O)%O -> W[r][kk][oo]

#define PB_CVT 6250                 // NN*128/4 / 256
#define PB_W0  (PB_CVT + 160)       // 320*128/256
#define PB_W1  (PB_W0 + 320)        // 640*128/256
#define PB_W2  (PB_W1 + 320)
#define PB_W3  (PB_W2 + 160)
#define PB_Q   (PB_W3 + 16)         // 16 graphs, one block each
#define PB_HIST (PB_Q + 256)        // 256 histogram blocks (bcnt pre-zeroed by memset)

__global__ __launch_bounds__(256) void prep_hist(
        const float* __restrict__ x, __hip_bfloat16* __restrict__ xb0,
        const float* __restrict__ qe, const float* __restrict__ qn_W,
        const float* __restrict__ qn_b, float* __restrict__ q,
        const float* __restrict__ W0, const float* __restrict__ root0, __hip_bfloat16* __restrict__ WT0,
        const float* __restrict__ W1, const float* __restrict__ root1, __hip_bfloat16* __restrict__ WT1,
        const float* __restrict__ W2, const float* __restrict__ root2, __hip_bfloat16* __restrict__ WT2,
        const float* __restrict__ W3, const float* __restrict__ root3, __hip_bfloat16* __restrict__ WT3,
        const int* __restrict__ edst, int* __restrict__ bcnt) {
    __shared__ float red[256];
    int blk = blockIdx.x, tid = threadIdx.x;
    if (blk < PB_CVT) {
        int i = blk * 256 + tid;              // float4 index
        float4 v = ((const float4*)x)[i];
        union { ushort4 u; __hip_bfloat16 h[4]; } o;
        o.h[0] = __float2bfloat16(v.x); o.h[1] = __float2bfloat16(v.y);
        o.h[2] = __float2bfloat16(v.z); o.h[3] = __float2bfloat16(v.w);
        ((ushort4*)xb0)[i] = o.u;
    } else if (blk < PB_W3) {
        const float* W; const float* root; __hip_bfloat16* WT; int O, logO, base;
        if (blk < PB_W0)      { W = W0; root = root0; WT = WT0; O = 64;  logO = 6; base = PB_CVT; }
        else if (blk < PB_W1) { W = W1; root = root1; WT = WT1; O = 128; logO = 7; base = PB_W0; }
        else if (blk < PB_W2) { W = W2; root = root2; WT = WT2; O = 128; logO = 7; base = PB_W1; }
        else                  { W = W3; root = root3; WT = WT3; O = 64;  logO = 6; base = PB_W2; }
        int idx = (blk - base) * 256 + tid;
        int og = idx >> 7, kk = idx & 127;
        float v;
        if (og < O) v = root[(size_t)kk * O + og];
        else {
            int t2 = og - O;
            int r = t2 >> logO, oo = t2 & (O - 1);
            v = W[((size_t)r * 128 + kk) * O + oo];
        }
        WT[idx] = __float2bfloat16(v);
    } else if (blk < PB_Q) {
        // q projection: K=768 split 4 ways (chain length 192), LDS reduce
        int g = blk - PB_W3;
        int o = tid & 63, kc = tid >> 6;
        const float* qr = qe + (size_t)g * QD;
        float s = 0.f;
        int k0 = kc * 192;
        for (int k = k0; k < k0 + 192; ++k)
            s = fmaf(qr[k], qn_W[(size_t)k * 64 + o], s);
        red[tid] = s;
        __syncthreads();
        if (tid < 64) {
            float t = red[tid] + red[tid + 64] + red[tid + 128] + red[tid + 192] + qn_b[o];
            q[g * 64 + o] = fmaxf(t, 0.f);
        }
    } else {
        // bucket histogram: 256 logical blocks, fixed stride 65536
        __shared__ int h[NBUCK];
        int hb = blk - PB_Q;
        for (int i = tid; i < NBUCK; i += 256) h[i] = 0;
        __syncthreads();
        for (int e = hb * 256 + tid; e < EE; e += 256 * 256)
            atomicAdd(&h[edst[e] >> 8], 1);
        __syncthreads();
        for (int i = tid; i < NBUCK; i += 256) if (h[i]) atomicAdd(&bcnt[i], h[i]);
    }
}

// ---------- CSR build: scan, bin, fine (proven kernels, unchanged) ----------

__global__ void bucket_scan(const int* __restrict__ bcnt, int* __restrict__ bbase,
                            int* __restrict__ bcur) {
    __shared__ int wt[4];
    int tid = threadIdx.x, lane = tid & 63, w = tid >> 6;
    int v = (tid < NBUCK) ? bcnt[tid] : 0;
    int sc = v;
#pragma unroll
    for (int off = 1; off < 64; off <<= 1) {
        int t = __shfl_up(sc, off, 64);
        if (lane >= off) sc += t;
    }
    if (lane == 63) wt[w] = sc;
    __syncthreads();
    int wbase = 0;
    for (int ww = 0; ww < w; ++ww) wbase += wt[ww];
    int excl = wbase + sc - v;
    if (tid <= NBUCK) bbase[tid] = excl;   // tid==NBUCK gets total == EE
    if (tid < NBUCK) bcur[tid] = excl;
}

__global__ __launch_bounds__(256) void bin_edges(const int* __restrict__ src,
                                                 const int* __restrict__ dst,
                                                 const int* __restrict__ et,
                                                 int* __restrict__ bcur,
                                                 unsigned* __restrict__ binned) {
    __shared__ int lcnt[NBUCK];
    __shared__ int lbase[NBUCK];
    int tid = threadIdx.x;
    int e0 = blockIdx.x * EPB, e1 = min(e0 + EPB, EE);
    for (int base = e0; base < e1; base += 2048) {
        for (int i = tid; i < NBUCK; i += 256) lcnt[i] = 0;
        __syncthreads();
        unsigned ent[8]; int bk[8], rk[8];
#pragma unroll
        for (int k = 0; k < 8; ++k) {
            int e = base + k * 256 + tid;
            if (e < e1) {
                int d = dst[e];
                bk[k] = d >> 8;
                ent[k] = ((unsigned)src[e] << 10) | ((unsigned)et[e] << 8) | (unsigned)(d & 255);
                rk[k] = atomicAdd(&lcnt[bk[k]], 1);
            } else bk[k] = -1;
        }
        __syncthreads();
        for (int i = tid; i < NBUCK; i += 256)
            lbase[i] = lcnt[i] ? atomicAdd(&bcur[i], lcnt[i]) : 0;
        __syncthreads();
#pragma unroll
        for (int k = 0; k < 8; ++k)
            if (bk[k] >= 0) binned[lbase[bk[k]] + rk[k]] = ent[k];
        __syncthreads();
    }
}

__global__ __launch_bounds__(256) void csr_fine(const int* __restrict__ bbase,
                                                const unsigned* __restrict__ binned,
                                                int* __restrict__ csr,
                                                int* __restrict__ offsets,
                                                int4* __restrict__ cnt4) {
    __shared__ int cnt[1024];   // 256 nodes x 4 rels
    __shared__ int wt[4];
    int b = blockIdx.x, tid = threadIdx.x, lane = tid & 63, w = tid >> 6;
    int seg0 = bbase[b], seg1 = bbase[b + 1];
    for (int i = tid; i < 1024; i += 256) cnt[i] = 0;
    __syncthreads();
    for (int e = seg0 + tid; e < seg1; e += 256) {
        unsigned u = binned[e];
        atomicAdd(&cnt[(u & 255) * 4 + ((u >> 8) & 3)], 1);
    }
    __syncthreads();
    int c0 = cnt[tid * 4], c1 = cnt[tid * 4 + 1], c2 = cnt[tid * 4 + 2], c3 = cnt[tid * 4 + 3];
    int s = c0 + c1 + c2 + c3;
    int sc = s;
#pragma unroll
    for (int off = 1; off < 64; off <<= 1) {
        int t = __shfl_up(sc, off, 64);
        if (lane >= off) sc += t;
    }
    if (lane == 63) wt[w] = sc;
    __syncthreads();
    int wbase = 0;
    for (int ww = 0; ww < w; ++ww) wbase += wt[ww];
    int excl = wbase + sc - s;
    cnt[tid * 4]     = excl;
    cnt[tid * 4 + 1] = excl + c0;
    cnt[tid * 4 + 2] = excl + c0 + c1;
    cnt[tid * 4 + 3] = excl + c0 + c1 + c2;
    int node = b * 256 + tid;
    if (node < NN) {
        offsets[node] = seg0 + excl;
        cnt4[node] = make_int4(c0, c1, c2, c3);
    }
    if (b == NBUCK - 1 && tid == 0) offsets[NN] = EE;
    __syncthreads();
    for (int e = seg0 + tid; e < seg1; e += 256) {
        unsigned u = binned[e];
        int r = atomicAdd(&cnt[(u & 255) * 4 + ((u >> 8) & 3)], 1);
        csr[seg0 + r] = (int)(((u >> 10) << 2) | ((u >> 8) & 3));   // (src<<2)|rel
    }
}

// ---------- denseT: HT[N][5O] = X[N][128] @ WT^T (bf16, no epilogue) ----------
// 128-row x 160-col tiles; MFMA fragment machinery identical to the proven
// dense5 (K-chunked LDS staging of weights, a-frags direct from X rows).

template <int OC5>   // 320 or 640
__global__ __launch_bounds__(256) void denseT(const __hip_bfloat16* __restrict__ X,
                                              const __hip_bfloat16* __restrict__ WT,
                                              __hip_bfloat16* __restrict__ HT) {
    __shared__ char lds[20480];
    constexpr int NCT = 10;               // 160 cols per block
    constexpr int NCTILES = OC5 / 160;
    int tid = threadIdx.x, wave = tid >> 6, lane = tid & 63;
    int quad = lane >> 4, l15 = lane & 15;
    int ct = blockIdx.x % NCTILES, rt = blockIdx.x / NCTILES;
    int mbase = rt * 128 + wave * 32;
    int cbase = ct * 160;
    const __bf16* Ws = (const __bf16*)WT;

    f32x4 acc[2][NCT];
#pragma unroll
    for (int mt = 0; mt < 2; ++mt)
#pragma unroll
        for (int t = 0; t < NCT; ++t) acc[mt][t] = f32x4{0, 0, 0, 0};

    int arow0 = min(mbase + l15, NN - 1);
    int arow1 = min(mbase + 16 + l15, NN - 1);
    const __bf16* ap0 = (const __bf16*)X + (size_t)arow0 * 128;
    const __bf16* ap1 = (const __bf16*)X + (size_t)arow1 * 128;

    for (int kc = 0; kc < 2; ++kc) {
        int k0 = kc * 64;
        __syncthreads();
#pragma unroll
        for (int i = 0; i < 5; ++i) {     // 1280 fragments of 16B
            int f = tid + i * 256;
            int fl = f & 63;
            int t = f >> 7;
            int ks = (f >> 6) & 1;
            int og = cbase + t * 16 + (fl & 15);
            int kk = k0 + ks * 32 + ((fl >> 4) & 3) * 8;
            *(uint4*)(lds + f * 16) = *(const uint4*)(Ws + (size_t)og * 128 + kk);
        }
        __syncthreads();
#pragma unroll
        for (int ks = 0; ks < 2; ++ks) {
            bf16x8 a0 = *(const bf16x8*)(ap0 + k0 + ks * 32 + quad * 8);
            bf16x8 a1 = *(const bf16x8*)(ap1 + k0 + ks * 32 + quad * 8);
#pragma unroll
            for (int t = 0; t < NCT; ++t) {
                bf16x8 b = *(const bf16x8*)(lds + ((t * 2 + ks) * 64 + lane) * 16);
                acc[0][t] = __builtin_amdgcn_mfma_f32_16x16x32_bf16(a0, b, acc[0][t], 0, 0, 0);
                acc[1][t] = __builtin_amdgcn_mfma_f32_16x16x32_bf16(a1, b, acc[1][t], 0, 0, 0);
            }
        }
    }
    __syncthreads();

    // epilogue: per-wave LDS tile [16][160] bf16, then 16B-chunk stores
    __hip_bfloat16* tp = (__hip_bfloat16*)(lds + wave * 5120);
    for (int mt = 0; mt < 2; ++mt) {
        int m0 = mbase + mt * 16;
#pragma unroll
        for (int t = 0; t < NCT; ++t) {
            int col = t * 16 + l15;
#pragma unroll
            for (int reg = 0; reg < 4; ++reg)
                tp[(quad * 4 + reg) * 160 + col] = __float2bfloat16(acc[mt][t][reg]);
        }
#pragma unroll
        for (int p = 0; p < 5; ++p) {     // 16 rows x 320 B
            int b = p * 1024 + lane * 16;
            int row = b / 320;
            int cb = b - row * 320;
            if (m0 + row < NN)
                *(uint4*)((char*)HT + (size_t)(m0 + row) * (OC5 * 2) + cbase * 2 + cb) =
                    *(const uint4*)((const char*)tp + b);
        }
    }
}

// ---------- gsum: out[i] = HT[i,self] + bias + sum_e inv_c[rel] * HT[src,rel] ----------
// Flat edge walk (no segments, no padding). csr entry = (src<<2)|rel. Scalar
// decode via readlane -> SGPR soffset gathers; 4-deep unroll; HW OOB masks
// window tails. MODE 0: O=64, relu, [h|q[batch]] bf16. MODE 1: O=128, relu
// bf16. MODE 2: O=64, fp32 out, no relu.

template <int O, int MODE>
__global__ __launch_bounds__(256) void gsum(const __hip_bfloat16* __restrict__ HT,
        const int* __restrict__ offsets, const int4* __restrict__ cnt4,
        const int* __restrict__ csr, const float* __restrict__ bias,
        const float* __restrict__ q, const int* __restrict__ batch,
        __hip_bfloat16* __restrict__ xnext, float* __restrict__ out) {
    constexpr int STRIDE = 5 * O * 2;     // HT row bytes: 640 / 1280
    constexpr int ROWB = O * 2;           // per-rel slice bytes: 128 / 256
    int tid = threadIdx.x;
    int lane = tid & 63;
    int gw = blockIdx.x * 4 + (tid >> 6);

    v4i hsrd, csrd;
    hsrd.x = (int)(unsigned)(size_t)HT; hsrd.y = (int)((size_t)HT >> 32);
    hsrd.z = NN * STRIDE; hsrd.w = 0x00020000;
    csrd.x = (int)(unsigned)(size_t)csr; csrd.y = (int)((size_t)csr >> 32);
    csrd.z = EE * 4; csrd.w = 0x00020000;

    for (int n0 = gw; n0 < NN; n0 += AGG_STRIDE) {
        int node = __builtin_amdgcn_readfirstlane(n0);
        int e0 = __builtin_amdgcn_readfirstlane(offsets[node]);
        int4 c4 = cnt4[node];
        int cs0 = __builtin_amdgcn_readfirstlane(c4.x);
        int cs1 = __builtin_amdgcn_readfirstlane(c4.y);
        int cs2 = __builtin_amdgcn_readfirstlane(c4.z);
        int cs3 = __builtin_amdgcn_readfirstlane(c4.w);
        int tcnt = cs0 + cs1 + cs2 + cs3;
        float inv0 = 1.f / (float)max(cs0, 1);
        float inv1 = 1.f / (float)max(cs1, 1);
        float inv2 = 1.f / (float)max(cs2, 1);
        float inv3 = 1.f / (float)max(cs3, 1);
        float a0 = 0.f, a1 = 0.f;

        if (O == 128) {
            for (int wb = 0; wb < tcnt; wb += 64) {
                int pkw = __llvm_amdgcn_raw_buffer_load_i32(csrd, (e0 + wb + lane) * 4, 0, 0);
                int m = min(64, tcnt - wb);
                for (int j = 0; j < m; j += 4) {
                    int sb[4]; float scv[4];
#pragma unroll
                    for (int k2 = 0; k2 < 4; ++k2) {
                        int pk = __builtin_amdgcn_readlane(pkw, j + k2);
                        int rel = pk & 3;
                        scv[k2] = (rel & 2) ? ((rel & 1) ? inv3 : inv2)
                                            : ((rel & 1) ? inv1 : inv0);
                        sb[k2] = (j + k2 < m) ? ((pk >> 2) * STRIDE + (rel + 1) * ROWB)
                                              : 0x7F000000;
                    }
                    unsigned u[4];
#pragma unroll
                    for (int k2 = 0; k2 < 4; ++k2)
                        u[k2] = (unsigned)__llvm_amdgcn_raw_buffer_load_i32(hsrd, lane * 4, sb[k2], 0);
#pragma unroll
                    for (int k2 = 0; k2 < 4; ++k2) {
                        a0 += scv[k2] * bflo(u[k2]);
                        a1 += scv[k2] * bfhi(u[k2]);
                    }
                }
            }
        } else {
            // 2 edges per pass: lanes 0-31 slot j, lanes 32-63 slot j+1
            int colb = (lane & 31) * 4;
            bool hi_half = lane >= 32;
            for (int wb = 0; wb < tcnt; wb += 64) {
                int pkw = __llvm_amdgcn_raw_buffer_load_i32(csrd, (e0 + wb + lane) * 4, 0, 0);
                int m = min(64, tcnt - wb);
                for (int j = 0; j < m; j += 4) {
                    int sbs[4]; float scs[4];
#pragma unroll
                    for (int k2 = 0; k2 < 4; ++k2) {
                        int pk = __builtin_amdgcn_readlane(pkw, j + k2);
                        int rel = pk & 3;
                        scs[k2] = (rel & 2) ? ((rel & 1) ? inv3 : inv2)
                                            : ((rel & 1) ? inv1 : inv0);
                        sbs[k2] = (j + k2 < m) ? ((pk >> 2) * STRIDE + (rel + 1) * ROWB)
                                               : 0x7F000000;
                    }
                    float sc0 = hi_half ? scs[1] : scs[0];
                    float sc1 = hi_half ? scs[3] : scs[2];
                    int sb0 = hi_half ? sbs[1] : sbs[0];
                    int sb1 = hi_half ? sbs[3] : sbs[2];
                    unsigned u0 = (unsigned)__llvm_amdgcn_raw_buffer_load_i32(hsrd, sb0 + colb, 0, 0);
                    unsigned u1 = (unsigned)__llvm_amdgcn_raw_buffer_load_i32(hsrd, sb1 + colb, 0, 0);
                    a0 += sc0 * bflo(u0) + sc1 * bflo(u1);
                    a1 += sc0 * bfhi(u0) + sc1 * bfhi(u1);
                }
            }
            a0 += __shfl_xor(a0, 32);
            a1 += __shfl_xor(a1, 32);
        }

        // epilogue
        if (MODE == 1) {
            unsigned us = (unsigned)__llvm_amdgcn_raw_buffer_load_i32(hsrd, lane * 4, node * STRIDE, 0);
            float2 bv = *(const float2*)(bias + lane * 2);
            float o0 = fmaxf(bflo(us) + bv.x + a0, 0.f);
            float o1 = fmaxf(bfhi(us) + bv.y + a1, 0.f);
            __hip_bfloat16 h0 = __float2bfloat16(o0), h1 = __float2bfloat16(o1);
            ushort2 pkd;
            pkd.x = *(unsigned short*)&h0; pkd.y = *(unsigned short*)&h1;
            *(ushort2*)((char*)xnext + (size_t)node * 256 + lane * 4) = pkd;
        } else if (MODE == 0) {
            if (lane < 32) {
                unsigned us = (unsigned)__llvm_amdgcn_raw_buffer_load_i32(hsrd, lane * 4, node * STRIDE, 0);
                float2 bv = *(const float2*)(bias + lane * 2);
                float o0 = fmaxf(bflo(us) + bv.x + a0, 0.f);
                float o1 = fmaxf(bfhi(us) + bv.y + a1, 0.f);
                __hip_bfloat16 h0 = __float2bfloat16(o0), h1 = __float2bfloat16(o1);
                ushort2 pkd;
                pkd.x = *(unsigned short*)&h0; pkd.y = *(unsigned short*)&h1;
                *(ushort2*)((char*)xnext + (size_t)node * 256 + lane * 4) = pkd;
            } else {
                int g = batch[node];
                float2 qv = *(const float2*)(q + g * 64 + (lane - 32) * 2);
                __hip_bfloat16 h0 = __float2bfloat16(qv.x), h1 = __float2bfloat16(qv.y);
                ushort2 pkd;
                pkd.x = *(unsigned short*)&h0; pkd.y = *(unsigned short*)&h1;
                *(ushort2*)((char*)xnext + (size_t)node * 256 + 128 + (lane - 32) * 4) = pkd;
            }
        } else {
            if (lane < 32) {
                unsigned us = (unsigned)__llvm_amdgcn_raw_buffer_load_i32(hsrd, lane * 4, node * STRIDE, 0);
                float2 bv = *(const float2*)(bias + lane * 2);
                float2 ov;
                ov.x = bflo(us) + bv.x + a0;
                ov.y = bfhi(us) + bv.y + a1;
                *(float2*)(out + (size_t)node * 64 + lane * 2) = ov;
            }
        }
    }
}

// ---------- launch ----------

static inline size_t rup(size_t x) { return (x + 255) & ~(size_t)255; }

extern "C" void kernel_launch(void* const* d_in, const int* in_sizes, int n_in,
                              void* d_out, int out_size, void* d_ws, size_t ws_size,
                              hipStream_t stream) {
    const float* x      = (const float*)d_in[0];
    const int*   esrc   = (const int*)d_in[1];
    const int*   edst   = esrc + EE;
    const int*   eattr  = (const int*)d_in[2];
    const int*   batch  = (const int*)d_in[3];
    const float* qe     = (const float*)d_in[4];
    const float* qn_W   = (const float*)d_in[5];
    const float* qn_b   = (const float*)d_in[6];
    const float* W0 = (const float*)d_in[7],  *root0 = (const float*)d_in[8],  *b0 = (const float*)d_in[9];
    const float* W1 = (const float*)d_in[10], *root1 = (const float*)d_in[11], *b1 = (const float*)d_in[12];
    const float* W2 = (const float*)d_in[13], *root2 = (const float*)d_in[14], *b2 = (const float*)d_in[15];
    const float* W3 = (const float*)d_in[16], *root3 = (const float*)d_in[17], *b3 = (const float*)d_in[18];
    float* out = (float*)d_out;

    char* w = (char*)d_ws;
    float* q       = (float*)w;  w += rup(GG * 64 * 4);
    int*   offsets = (int*)w;    w += rup(((size_t)NN + 1) * 4);
    int4*  cnt4    = (int4*)w;   w += rup((size_t)NN * 16);
    int*   bcnt    = (int*)w;    w += rup((size_t)NBUCK * 4);
    int*   bbase   = (int*)w;    w += rup(((size_t)NBUCK + 1) * 4);
    int*   bcur    = (int*)w;    w += rup((size_t)NBUCK * 4);
    unsigned* binned = (unsigned*)w; w += rup((size_t)EE * 4);
    int*   csr     = (int*)w;    w += rup((size_t)EE * 4);
    __hip_bfloat16* WT0 = (__hip_bfloat16*)w; w += rup((size_t)320 * 128 * 2);
    __hip_bfloat16* WT1 = (__hip_bfloat16*)w; w += rup((size_t)640 * 128 * 2);
    __hip_bfloat16* WT2 = (__hip_bfloat16*)w; w += rup((size_t)640 * 128 * 2);
    __hip_bfloat16* WT3 = (__hip_bfloat16*)w; w += rup((size_t)320 * 128 * 2);
    __hip_bfloat16* xb0 = (__hip_bfloat16*)w;  w += rup((size_t)NN * 128 * 2);
    __hip_bfloat16* xb1 = (__hip_bfloat16*)w;  w += rup((size_t)NN * 128 * 2);
    __hip_bfloat16* HT  = (__hip_bfloat16*)w;  w += rup((size_t)NN * 640 * 2);

    hipMemsetAsync(bcnt, 0, (size_t)NBUCK * 4, stream);

    // fused prep: conversion + weight transposes + q projection + histogram
    prep_hist<<<PB_HIST, 256, 0, stream>>>(x, xb0, qe, qn_W, qn_b, q,
                                           W0, root0, WT0, W1, root1, WT1,
                                           W2, root2, WT2, W3, root3, WT3,
                                           edst, bcnt);

    bucket_scan<<<1, 256, 0, stream>>>(bcnt, bbase, bcur);
    bin_edges<<<(EE + EPB - 1) / EPB, 256, 0, stream>>>(esrc, edst, eattr, bcur, binned);
    csr_fine<<<NBUCK, 256, 0, stream>>>(bbase, binned, csr, offsets, cnt4);

    int rowtiles = (NN + 127) / 128;       // 391

    // layer 0: xb0 -> HT(320) -> [h|q] xb1
    denseT<320><<<rowtiles * 2, 256, 0, stream>>>(xb0, WT0, HT);
    gsum<64, 0><<<AGG_GRID, 256, 0, stream>>>(HT, offsets, cnt4, csr, b0, q, batch, xb1, nullptr);

    // layer 1: xb1 -> HT(640) -> xb0
    denseT<640><<<rowtiles * 4, 256, 0, stream>>>(xb1, WT1, HT);
    gsum<128, 1><<<AGG_GRID, 256, 0, stream>>>(HT, offsets, cnt4, csr, b1, nullptr, nullptr, xb0, nullptr);

    // layer 2: xb0 -> HT(640) -> xb1
    denseT<640><<<rowtiles * 4, 256, 0, stream>>>(xb0, WT2, HT);
    gsum<128, 1><<<AGG_GRID, 256, 0, stream>>>(HT, offsets, cnt4, csr, b2, nullptr, nullptr, xb1, nullptr);

    // layer 3: xb1 -> HT(320) -> fp32 out
    denseT<320><<<rowtiles * 2, 256, 0, stream>>>(xb1, WT3, HT);
    gsum<64, 2><<<AGG_GRID, 256, 0, stream>>>(HT, offsets, cnt4, csr, b3, nullptr, nullptr, nullptr, out);
}